// Round 6
// baseline (281.387 us; speedup 1.0000x reference)
//
#include <hip/hip_runtime.h>
#include <cstdint>

#define HEADS 16
#define DH 64
#define SEQ 2048
#define BATCH 4
#define DIM 1024
#define MTOT (BATCH*SEQ)   // 8192
#define NQKV (3*DIM)       // 3072

typedef short bf16x8 __attribute__((ext_vector_type(8)));
typedef float f32x4 __attribute__((ext_vector_type(4)));
typedef float f32x16 __attribute__((ext_vector_type(16)));

__device__ __forceinline__ unsigned short f2bf(float f) {
  union { float fv; unsigned int u; } c; c.fv = f;
  unsigned int u = c.u;
  u += 0x7FFFu + ((u >> 16) & 1u);   // round-to-nearest-even
  return (unsigned short)(u >> 16);
}

// pack two fp32 -> two bf16 (round-half-up) in one u32
__device__ __forceinline__ unsigned int pkbf(float lo, float hi) {
  union { float fv; unsigned int u; } a, b; a.fv = lo; b.fv = hi;
  return ((a.u + 0x8000u) >> 16) | ((b.u + 0x8000u) & 0xFFFF0000u);
}

__device__ __forceinline__ f32x4 mfma16(bf16x8 a, bf16x8 b, f32x4 c) {
  return __builtin_amdgcn_mfma_f32_16x16x32_bf16(a, b, c, 0, 0, 0);
}
__device__ __forceinline__ f32x16 mfma32(bf16x8 a, bf16x8 b, f32x16 c) {
  return __builtin_amdgcn_mfma_f32_32x32x16_bf16(a, b, c, 0, 0, 0);
}

typedef const __attribute__((address_space(1))) unsigned int* gas_ptr;
typedef __attribute__((address_space(3))) unsigned int* las_ptr;
__device__ __forceinline__ void gl2lds16(const void* g, void* l) {
  __builtin_amdgcn_global_load_lds((gas_ptr)g, (las_ptr)l, 16, 0, 0);
}

// Q pre-scale: Dh^-0.5 * log2(e)  (softmax done in exp2 domain)
#define QSCALE 0.18033688011112042f

// ---------------------------------------------------------------- fused prep
// blocks [0, 8192): cast x -> bf16
// blocks [8192, 8192+3072): transpose+cast w_qkv
// blocks [8192+3072, +1024): transpose+cast w_out
#define CAST_BLKS (MTOT * DIM / 4 / 256)       // 8192
#define TQKV_BLKS ((NQKV / 32) * (DIM / 32))   // 3072
#define TOUT_BLKS ((DIM / 32) * (DIM / 32))    // 1024

__global__ __launch_bounds__(256) void prep(
    const float* __restrict__ x, const float* __restrict__ w_qkv,
    const float* __restrict__ w_out, unsigned short* __restrict__ xb,
    unsigned short* __restrict__ wqkv_t, unsigned short* __restrict__ wout_t) {
  __shared__ float tile[32][33];
  int blk = blockIdx.x;
  if (blk < CAST_BLKS) {
    int i = blk * 256 + threadIdx.x;
    float4 v = reinterpret_cast<const float4*>(x)[i];
    uint2 o;
    o.x = (unsigned int)f2bf(v.x) | ((unsigned int)f2bf(v.y) << 16);
    o.y = (unsigned int)f2bf(v.z) | ((unsigned int)f2bf(v.w) << 16);
    reinterpret_cast<uint2*>(xb)[i] = o;
    return;
  }
  blk -= CAST_BLKS;
  const float* in; unsigned short* out; int R, C, bx, by;
  if (blk < TQKV_BLKS) {
    in = w_qkv; out = wqkv_t; R = DIM; C = NQKV;
    bx = blk % (NQKV / 32); by = blk / (NQKV / 32);
  } else {
    blk -= TQKV_BLKS;
    in = w_out; out = wout_t; R = DIM; C = DIM;
    bx = blk % (DIM / 32); by = blk / (DIM / 32);
  }
  int c0 = bx * 32, r0 = by * 32;
  int tx = threadIdx.x & 31, ty = threadIdx.x >> 5;  // ty 0..7
  for (int i = 0; i < 32; i += 8)
    tile[ty + i][tx] = in[(size_t)(r0 + ty + i) * C + c0 + tx];
  __syncthreads();
  for (int i = 0; i < 32; i += 8)
    out[(size_t)(c0 + ty + i) * R + r0 + tx] = f2bf(tile[tx][ty + i]);
}

// ---------------------------------------------------------------- QKV GEMM (m97 structure)
// Writes Q,K as [b,h,n,d] and V TRANSPOSED as [b,h,d,n].
#define BM 128
#define BN 128
#define BK 32
#define LDT 32   // UNPADDED: required by global_load_lds wave-uniform layout

__global__ __launch_bounds__(256) void gemm_qkv(
    const unsigned short* __restrict__ A, const unsigned short* __restrict__ Bt,
    unsigned short* __restrict__ Q, unsigned short* __restrict__ K,
    unsigned short* __restrict__ V) {
  __shared__ unsigned short sA[BM * LDT];
  __shared__ unsigned short sB[BN * LDT];
  const int KD = 1024;
  int m0 = blockIdx.y * BM;
  int n0 = blockIdx.x * BN;
  int t = threadIdx.x;
  int lane = t & 63, w = t >> 6;
  int wm = (w >> 1) * 64, wn = (w & 1) * 64;
  int fr = lane & 15, fq = (lane >> 4) * 8;

  const unsigned short* gA = &A[(size_t)(m0 + w * 16 + (lane >> 2)) * KD + (lane & 3) * 8];
  const unsigned short* gB = &Bt[(size_t)(n0 + w * 16 + (lane >> 2)) * KD + (lane & 3) * 8];
  char* lA = (char*)sA + w * 1024;
  char* lB = (char*)sB + w * 1024;

  f32x4 acc[4][4];
#pragma unroll
  for (int i = 0; i < 4; i++)
#pragma unroll
    for (int j = 0; j < 4; j++) { f32x4 z = {0.f, 0.f, 0.f, 0.f}; acc[i][j] = z; }

  for (int k0 = 0; k0 < KD; k0 += BK) {
    gl2lds16(gA + k0, lA);
    gl2lds16(gA + (size_t)64 * KD + k0, lA + 4096);
    gl2lds16(gB + k0, lB);
    gl2lds16(gB + (size_t)64 * KD + k0, lB + 4096);
    __syncthreads();
    bf16x8 af[4], bfr[4];
#pragma unroll
    for (int mt = 0; mt < 4; mt++)
      af[mt] = *reinterpret_cast<const bf16x8*>(&sA[(wm + mt * 16 + fr) * LDT + fq]);
#pragma unroll
    for (int nt = 0; nt < 4; nt++)
      bfr[nt] = *reinterpret_cast<const bf16x8*>(&sB[(wn + nt * 16 + fr) * LDT + fq]);
#pragma unroll
    for (int mt = 0; mt < 4; mt++)
#pragma unroll
      for (int nt = 0; nt < 4; nt++)
        acc[mt][nt] = mfma16(af[mt], bfr[nt], acc[mt][nt]);
    __syncthreads();
  }
  // epilogue: scatter to q/k [b][h][n][d], v -> [b][h][d][n]
  int rowq = (lane >> 4) * 4;
#pragma unroll
  for (int mt = 0; mt < 4; mt++)
#pragma unroll
    for (int nt = 0; nt < 4; nt++)
#pragma unroll
      for (int r = 0; r < 4; r++) {
        int m = m0 + wm + mt * 16 + rowq + r;
        int ncol = n0 + wn + nt * 16 + fr;
        int which = ncol >> 10;
        int hd = ncol & 1023;
        int b = m >> 11, nrow = m & 2047;
        float v = acc[mt][nt][r];
        if (which == 0) v *= QSCALE;  // Dh^-0.5 * log2(e)
        int bh = b * HEADS + (hd >> 6), d = hd & 63;
        if (which == 2) {
          V[((size_t)bh * DH + d) * SEQ + nrow] = f2bf(v);
        } else {
          unsigned short* dst = (which == 0) ? Q : K;
          dst[((size_t)bh * SEQ + nrow) * DH + d] = f2bf(v);
        }
      }
}

// ---------------------------------------------------------------- out-proj GEMM
__global__ __launch_bounds__(256) void gemm_out(
    const unsigned short* __restrict__ A, const unsigned short* __restrict__ Bt,
    const float* __restrict__ bias, float* __restrict__ C) {
  __shared__ unsigned short sA[BM * LDT];
  __shared__ unsigned short sB[BN * LDT];
  const int KD = 1024;
  int m0 = blockIdx.y * BM;
  int n0 = blockIdx.x * BN;
  int t = threadIdx.x;
  int lane = t & 63, w = t >> 6;
  int wm = (w >> 1) * 64, wn = (w & 1) * 64;
  int fr = lane & 15, fq = (lane >> 4) * 8;

  const unsigned short* gA = &A[(size_t)(m0 + w * 16 + (lane >> 2)) * KD + (lane & 3) * 8];
  const unsigned short* gB = &Bt[(size_t)(n0 + w * 16 + (lane >> 2)) * KD + (lane & 3) * 8];
  char* lA = (char*)sA + w * 1024;
  char* lB = (char*)sB + w * 1024;

  f32x4 acc[4][4];
#pragma unroll
  for (int i = 0; i < 4; i++)
#pragma unroll
    for (int j = 0; j < 4; j++) { f32x4 z = {0.f, 0.f, 0.f, 0.f}; acc[i][j] = z; }

  for (int k0 = 0; k0 < KD; k0 += BK) {
    gl2lds16(gA + k0, lA);
    gl2lds16(gA + (size_t)64 * KD + k0, lA + 4096);
    gl2lds16(gB + k0, lB);
    gl2lds16(gB + (size_t)64 * KD + k0, lB + 4096);
    __syncthreads();
    bf16x8 af[4], bfr[4];
#pragma unroll
    for (int mt = 0; mt < 4; mt++)
      af[mt] = *reinterpret_cast<const bf16x8*>(&sA[(wm + mt * 16 + fr) * LDT + fq]);
#pragma unroll
    for (int nt = 0; nt < 4; nt++)
      bfr[nt] = *reinterpret_cast<const bf16x8*>(&sB[(wn + nt * 16 + fr) * LDT + fq]);
#pragma unroll
    for (int mt = 0; mt < 4; mt++)
#pragma unroll
      for (int nt = 0; nt < 4; nt++)
        acc[mt][nt] = mfma16(af[mt], bfr[nt], acc[mt][nt]);
    __syncthreads();
  }
  int rowq = (lane >> 4) * 4;
#pragma unroll
  for (int mt = 0; mt < 4; mt++)
#pragma unroll
    for (int nt = 0; nt < 4; nt++)
#pragma unroll
      for (int r = 0; r < 4; r++) {
        int m = m0 + wm + mt * 16 + rowq + r;
        int ncol = n0 + wn + nt * 16 + fr;
        C[(size_t)m * DIM + ncol] = acc[mt][nt][r] + bias[ncol];
      }
}

// ---------------------------------------------------------------- flash attention
// grid (SEQ/256, HEADS, BATCH); 4 waves x 64 q-rows. Register-resident P
// (S^T trick + j-permutation, see R5). NEW: double-buffered K/Vt staging with
// register prefetch -- global loads for tile k+1 issued before compute of
// tile k (latency hidden under MFMA/VALU), ds_write after compute, ONE
// barrier per tile.
#define LDA 72
#define TBUF (64 * LDA)

__global__ __launch_bounds__(256, 2) void attention(
    const unsigned short* __restrict__ Qg, const unsigned short* __restrict__ Kg,
    const unsigned short* __restrict__ Vtg, unsigned short* __restrict__ Og) {
  __shared__ unsigned short smem[4 * TBUF];   // [buf][K|Vt], 36.9 KB
  int qb = blockIdx.x, h = blockIdx.y, b = blockIdx.z;
  size_t base = (size_t)(b * HEADS + h) * SEQ * DH;
  const unsigned short* Q = Qg + base;
  const unsigned short* K = Kg + base;
  const unsigned short* Vt = Vtg + base;
  int t = threadIdx.x, lane = t & 63, w = t >> 6;
  int m = lane & 31, kh = lane >> 5;
  int q0 = qb * 256 + w * 64;

  // Q frags for both 32-row halves (B-operand of S^T), held all kernel
  bf16x8 qf[2][4];
#pragma unroll
  for (int qh = 0; qh < 2; qh++)
#pragma unroll
    for (int kt = 0; kt < 4; kt++)
      qf[qh][kt] = *reinterpret_cast<const bf16x8*>(
          &Q[(size_t)(q0 + 32 * qh + m) * DH + kt * 16 + kh * 8]);

  f32x16 oaccT[2][2];   // [qh][dhalf], C layout: row=d', col=qrow
#pragma unroll
  for (int qh = 0; qh < 2; qh++)
#pragma unroll
    for (int dh = 0; dh < 2; dh++)
#pragma unroll
      for (int i = 0; i < 16; i++) oaccT[qh][dh][i] = 0.f;
  float rs[2] = {0.f, 0.f};

  int sr = t >> 2, sc = (t & 3) * 8;

  // preload tile 0 into buf0
  {
    uint4 rk0 = *(const uint4*)&K[(size_t)sr * DH + sc];
    uint4 rk1 = *(const uint4*)&K[(size_t)sr * DH + sc + 32];
    uint4 rv0 = *(const uint4*)&Vt[(size_t)sr * SEQ + sc];
    uint4 rv1 = *(const uint4*)&Vt[(size_t)sr * SEQ + sc + 32];
    *(uint4*)&smem[sr * LDA + sc]              = rk0;
    *(uint4*)&smem[sr * LDA + sc + 32]         = rk1;
    *(uint4*)&smem[TBUF + sr * LDA + sc]       = rv0;
    *(uint4*)&smem[TBUF + sr * LDA + sc + 32]  = rv1;
  }
  __syncthreads();

  for (int ti = 0; ti < SEQ / 64; ti++) {
    int cur = ti & 1;
    const unsigned short* cK = smem + cur * 2 * TBUF;
    const unsigned short* cV = cK + TBUF;
    bool more = (ti + 1) < SEQ / 64;
    uint4 rk0, rk1, rv0, rv1;
    if (more) {  // prefetch tile ti+1 (latency hidden by compute below)
      int j1 = (ti + 1) * 64;
      rk0 = *(const uint4*)&K[(size_t)(j1 + sr) * DH + sc];
      rk1 = *(const uint4*)&K[(size_t)(j1 + sr) * DH + sc + 32];
      rv0 = *(const uint4*)&Vt[(size_t)sr * SEQ + j1 + sc];
      rv1 = *(const uint4*)&Vt[(size_t)sr * SEQ + j1 + sc + 32];
    }

    // S^T = K·Q^T, exp2, pack P into registers (pp[qh][s'][p])
    unsigned int pp[2][8][2];
#pragma unroll
    for (int jt = 0; jt < 2; jt++) {
      bf16x8 kf[4];
#pragma unroll
      for (int kt = 0; kt < 4; kt++)
        kf[kt] = *reinterpret_cast<const bf16x8*>(
            &cK[(jt * 32 + m) * LDA + (2 * kt + kh) * 8]);
#pragma unroll
      for (int qh = 0; qh < 2; qh++) {
        f32x16 s;
#pragma unroll
        for (int i = 0; i < 16; i++) s[i] = 0.f;
#pragma unroll
        for (int kt = 0; kt < 4; kt++)
          s = mfma32(kf[kt], qf[qh][kt], s);
        float e[16];
#pragma unroll
        for (int i = 0; i < 16; i++) e[i] = __builtin_amdgcn_exp2f(s[i]);
        float t0 = (e[0] + e[1]) + (e[2] + e[3]);
        float t1 = (e[4] + e[5]) + (e[6] + e[7]);
        float t2 = (e[8] + e[9]) + (e[10] + e[11]);
        float t3 = (e[12] + e[13]) + (e[14] + e[15]);
        rs[qh] += (t0 + t1) + (t2 + t3);
#pragma unroll
        for (int sl = 0; sl < 4; sl++) {
          pp[qh][4 * jt + sl][0] = pkbf(e[4 * sl + 0], e[4 * sl + 1]);
          pp[qh][4 * jt + sl][1] = pkbf(e[4 * sl + 2], e[4 * sl + 3]);
        }
      }
    }

    // O^T += Vt(π) @ P^T
#pragma unroll
    for (int kb = 0; kb < 4; kb++) {
#pragma unroll
      for (int dh = 0; dh < 2; dh++) {
        union { uint2 u[2]; bf16x8 v; } ac;
        ac.u[0] = *(const uint2*)&cV[(32 * dh + m) * LDA + 16 * kb + 4 * kh];
        ac.u[1] = *(const uint2*)&cV[(32 * dh + m) * LDA + 16 * kb + 8 + 4 * kh];
#pragma unroll
        for (int qh = 0; qh < 2; qh++) {
          union { unsigned int u[4]; bf16x8 v; } bc;
          bc.u[0] = pp[qh][2 * kb][0];
          bc.u[1] = pp[qh][2 * kb][1];
          bc.u[2] = pp[qh][2 * kb + 1][0];
          bc.u[3] = pp[qh][2 * kb + 1][1];
          oaccT[qh][dh] = mfma32(ac.v, bc.v, oaccT[qh][dh]);
        }
      }
    }

    if (more) {  // stage tile ti+1 into the other buffer
      unsigned short* nK = smem + (1 - cur) * 2 * TBUF;
      unsigned short* nV = nK + TBUF;
      *(uint4*)&nK[sr * LDA + sc]      = rk0;
      *(uint4*)&nK[sr * LDA + sc + 32] = rk1;
      *(uint4*)&nV[sr * LDA + sc]      = rv0;
      *(uint4*)&nV[sr * LDA + sc + 32] = rv1;
    }
    __syncthreads();
  }

  // complete rowsums (other 32 j's live in the partner half-wave)
  float inv[2];
#pragma unroll
  for (int qh = 0; qh < 2; qh++) {
    float tot = rs[qh] + __shfl_xor(rs[qh], 32);
    inv[qh] = 1.0f / tot;
  }

  // epilogue: normalize, transpose O^T -> O via per-wave LDS (stride 36 dwords),
  // then coalesced uint4 global stores. smem reused: wave w gets 4608 B.
  unsigned int* ew = (unsigned int*)smem + (size_t)w * 32 * 36;
#pragma unroll
  for (int qh = 0; qh < 2; qh++) {
#pragma unroll
    for (int dh = 0; dh < 2; dh++)
#pragma unroll
      for (int sl = 0; sl < 4; sl++) {
        unsigned int u0 = pkbf(oaccT[qh][dh][4 * sl + 0] * inv[qh],
                               oaccT[qh][dh][4 * sl + 1] * inv[qh]);
        unsigned int u1 = pkbf(oaccT[qh][dh][4 * sl + 2] * inv[qh],
                               oaccT[qh][dh][4 * sl + 3] * inv[qh]);
        uint2 pk; pk.x = u0; pk.y = u1;
        *(uint2*)&ew[m * 36 + 16 * dh + 4 * sl + 2 * kh] = pk;
      }
    // wave-private region: lgkmcnt ordering within wave suffices (no barrier)
    int mr = lane >> 3, ch = lane & 7;
#pragma unroll
    for (int it = 0; it < 4; it++) {
      uint4 vv = *(const uint4*)&ew[(8 * it + mr) * 36 + ch * 4];
      int n = q0 + 32 * qh + 8 * it + mr;
      *(uint4*)&Og[((size_t)(b * SEQ + n)) * DIM + h * DH + ch * 8] = vv;
    }
  }
}

// ---------------------------------------------------------------- launch
extern "C" void kernel_launch(void* const* d_in, const int* in_sizes, int n_in,
                              void* d_out, int out_size, void* d_ws, size_t ws_size,
                              hipStream_t stream) {
  const float* x     = (const float*)d_in[0];  // [4,2048,1024]
  const float* w_qkv = (const float*)d_in[1];  // [1024,3072]
  const float* w_out = (const float*)d_in[2];  // [1024,1024]
  const float* b_out = (const float*)d_in[3];  // [1024]
  float* out = (float*)d_out;                  // [4,2048,1024]

  char* ws = (char*)d_ws;
  unsigned short* xb     = (unsigned short*)ws; ws += (size_t)MTOT * DIM * 2;
  unsigned short* wqkv_t = (unsigned short*)ws; ws += (size_t)NQKV * DIM * 2;
  unsigned short* wout_t = (unsigned short*)ws; ws += (size_t)DIM * DIM * 2;
  unsigned short* qb_    = (unsigned short*)ws; ws += (size_t)BATCH * HEADS * SEQ * DH * 2;
  unsigned short* kb_    = (unsigned short*)ws; ws += (size_t)BATCH * HEADS * SEQ * DH * 2;
  unsigned short* vtb    = (unsigned short*)ws; ws += (size_t)BATCH * HEADS * SEQ * DH * 2;
  unsigned short* attnb  = (unsigned short*)ws; ws += (size_t)MTOT * DIM * 2;

  // 1. fused cast + weight transposes (one launch)
  prep<<<CAST_BLKS + TQKV_BLKS + TOUT_BLKS, 256, 0, stream>>>(
      x, w_qkv, w_out, xb, wqkv_t, wout_t);

  // 2. QKV projection: Q,K -> [b,h,n,d] (Q pre-scaled), V -> [b,h,d,n] (transposed)
  gemm_qkv<<<dim3(NQKV / BN, MTOT / BM), 256, 0, stream>>>(xb, wqkv_t, qb_, kb_, vtb);

  // 3. flash attention (register-resident P, double-buffered staging)
  attention<<<dim3(SEQ / 256, HEADS, BATCH), 256, 0, stream>>>(qb_, kb_, vtb, attnb);

  // 4. output projection + bias
  gemm_out<<<dim3(DIM / BN, MTOT / BM), 256, 0, stream>>>(attnb, wout_t, b_out, out);
}